// Round 6
// baseline (52.937 us; speedup 1.0000x reference)
//
#include <hip/hip_runtime.h>
#include <stdint.h>

#define T_TOK 8192
#define DM    1024
#define NE    8
#define BOT   64
#define HD    512
#define HD2   576   // 512 expert cols + 8 sg cols + 56 zero pad (bias folded into K)
#define PW    8     // tokens per prep block
#define NPREP (T_TOK / PW)   // 1024 prep blocks

typedef __attribute__((ext_vector_type(8))) short bf16x8;
typedef __attribute__((ext_vector_type(4))) short bf16x4;
typedef __attribute__((ext_vector_type(4))) float f32x4;

__device__ __forceinline__ ushort f2bf(float f) {
  union { float f; uint32_t u; } v; v.f = f;
  uint32_t r = (v.u + 0x7fffu + ((v.u >> 16) & 1u)) >> 16;
  return (ushort)r;
}

// ---- merged prep (blocks 0..1023) + weight transposes (1024..1295) ---------
__global__ __launch_bounds__(256, 2)
void prep_cvt_kernel(const float* __restrict__ x, const float* __restrict__ wg,
                     const float* __restrict__ Wd, const float* __restrict__ Wu,
                     const float* __restrict__ bu,
                     ushort* __restrict__ Xb, float* __restrict__ sg,
                     ushort* __restrict__ H2, ushort* __restrict__ WdT,
                     ushort* __restrict__ Wu2T) {
  __shared__ float part[4][PW][NE];
  __shared__ float sgl[PW][NE];
  __shared__ ushort tl[64][72];
  if (blockIdx.x < NPREP) {
    const int lane = threadIdx.x & 63;
    const int w    = threadIdx.x >> 6;
    const int t0   = blockIdx.x * PW;
    const int dd   = w * 256 + lane * 4;
    float4 wgr[4][2];
    #pragma unroll
    for (int j = 0; j < 4; ++j) {
      wgr[j][0] = *(const float4*)(wg + (size_t)(dd + j) * NE);
      wgr[j][1] = *(const float4*)(wg + (size_t)(dd + j) * NE + 4);
    }
    const int ebit = ((lane & 1) << 2) | (lane & 2) | ((lane >> 2) & 1);
    const float* xp = x + (size_t)t0 * DM + dd;
    float4 xv = *(const float4*)xp;
    #pragma unroll
    for (int tk = 0; tk < PW; ++tk) {
      float4 nxt = {};
      if (tk + 1 < PW) nxt = *(const float4*)(xp + (size_t)(tk + 1) * DM);
      bf16x4 xb;
      xb[0] = (short)f2bf(xv.x); xb[1] = (short)f2bf(xv.y);
      xb[2] = (short)f2bf(xv.z); xb[3] = (short)f2bf(xv.w);
      *(bf16x4*)(Xb + (size_t)(t0 + tk) * DM + dd) = xb;
      float a[NE] = {};
      const float* xs = (const float*)&xv;
      #pragma unroll
      for (int j = 0; j < 4; ++j) {
        const float xj = xs[j];
        const float* wr = (const float*)&wgr[j][0];
        #pragma unroll
        for (int e = 0; e < NE; ++e) a[e] += xj * wr[e];
      }
      float t0v[4];
      #pragma unroll
      for (int j = 0; j < 4; ++j) {
        float send = (lane & 1) ? a[j] : a[j + 4];
        float keep = (lane & 1) ? a[j + 4] : a[j];
        t0v[j] = keep + __shfl_xor(send, 1);
      }
      float t1v[2];
      #pragma unroll
      for (int j = 0; j < 2; ++j) {
        float send = (lane & 2) ? t0v[j] : t0v[j + 2];
        float keep = (lane & 2) ? t0v[j + 2] : t0v[j];
        t1v[j] = keep + __shfl_xor(send, 2);
      }
      {
        float send = (lane & 4) ? t1v[0] : t1v[1];
        float keep = (lane & 4) ? t1v[1] : t1v[0];
        float t2 = keep + __shfl_xor(send, 4);
        t2 += __shfl_xor(t2, 8);
        t2 += __shfl_xor(t2, 16);
        t2 += __shfl_xor(t2, 32);
        if (lane < NE) part[w][tk][ebit] = t2;
      }
      xv = nxt;
    }
    __syncthreads();
    const int tid = threadIdx.x;
    if (tid < PW) {
      float lg[NE];
      #pragma unroll
      for (int e = 0; e < NE; ++e)
        lg[e] = part[0][tid][e] + part[1][tid][e] + part[2][tid][e] + part[3][tid][e];
      int e0 = 0; float l0 = lg[0];
      #pragma unroll
      for (int e = 1; e < NE; ++e) if (lg[e] > l0) { l0 = lg[e]; e0 = e; }
      int e1 = -1; float l1 = -3.4e38f;
      #pragma unroll
      for (int e = 0; e < NE; ++e) if (e != e0 && lg[e] > l1) { l1 = lg[e]; e1 = e; }
      const float p1  = __expf(l1 - l0);
      const float inv = 1.f / (1.f + p1);
      const float g0 = 0.5f * inv, g1 = 0.5f * p1 * inv;   // ADAPTER_SCALE folded
      float g[NE];
      #pragma unroll
      for (int e = 0; e < NE; ++e) g[e] = (e == e0) ? g0 : ((e == e1) ? g1 : 0.f);
      #pragma unroll
      for (int e = 0; e < NE; ++e) sgl[tid][e] = g[e];
      *(float4*)(sg + (size_t)(t0 + tid) * NE)     = *(float4*)&g[0];
      *(float4*)(sg + (size_t)(t0 + tid) * NE + 4) = *(float4*)&g[4];
    }
    __syncthreads();
    if (tid < PW * 8) {
      const int tk = tid >> 3, ch = tid & 7;
      bf16x8 v;
      #pragma unroll
      for (int k = 0; k < 8; ++k)
        v[k] = (ch == 0) ? (short)f2bf(sgl[tk][k]) : (short)0;
      *(bf16x8*)(H2 + (size_t)(t0 + tk) * HD2 + HD + ch * 8) = v;
    }
  } else {
    const int rr = threadIdx.x >> 2;
    const int cc = (threadIdx.x & 3) * 16;
    const int bx = blockIdx.x - NPREP;
    if (bx < 128) {
      const int e  = bx >> 4;
      const int d0 = (bx & 15) * 64;
      const float* src = Wd + ((size_t)e * DM + d0 + rr) * BOT + cc;
      #pragma unroll
      for (int i = 0; i < 4; ++i) {
        float4 v = *(const float4*)(src + i * 4);
        tl[rr][cc + i * 4 + 0] = f2bf(v.x);
        tl[rr][cc + i * 4 + 1] = f2bf(v.y);
        tl[rr][cc + i * 4 + 2] = f2bf(v.z);
        tl[rr][cc + i * 4 + 3] = f2bf(v.w);
      }
      __syncthreads();
      bf16x8 o0, o1;
      #pragma unroll
      for (int k = 0; k < 8; ++k) o0[k] = (short)tl[cc + k][rr];
      #pragma unroll
      for (int k = 0; k < 8; ++k) o1[k] = (short)tl[cc + 8 + k][rr];
      ushort* dst = WdT + ((size_t)e * BOT + rr) * DM + d0 + cc;
      *(bf16x8*)dst       = o0;
      *(bf16x8*)(dst + 8) = o1;
    } else {
      const int b2 = bx - 128;
      const int n0 = (b2 >> 4) * 64;
      const int d0 = (b2 & 15) * 64;
      const int n  = n0 + rr;
      #pragma unroll
      for (int i = 0; i < 4; ++i) {
        float4 v;
        if (n < HD)           v = *(const float4*)(Wu + (size_t)n * DM + d0 + cc + i * 4);
        else if (n < HD + NE) v = *(const float4*)(bu + (size_t)(n - HD) * DM + d0 + cc + i * 4);
        else { v.x = 0.f; v.y = 0.f; v.z = 0.f; v.w = 0.f; }
        tl[rr][cc + i * 4 + 0] = f2bf(v.x);
        tl[rr][cc + i * 4 + 1] = f2bf(v.y);
        tl[rr][cc + i * 4 + 2] = f2bf(v.z);
        tl[rr][cc + i * 4 + 3] = f2bf(v.w);
      }
      __syncthreads();
      bf16x8 o0, o1;
      #pragma unroll
      for (int k = 0; k < 8; ++k) o0[k] = (short)tl[cc + k][rr];
      #pragma unroll
      for (int k = 0; k < 8; ++k) o1[k] = (short)tl[cc + 8 + k][rr];
      ushort* dst = Wu2T + (size_t)(d0 + rr) * HD2 + n0 + cc;
      *(bf16x8*)dst       = o0;
      *(bf16x8*)(dst + 8) = o1;
    }
  }
}

// ---- BM x 128 bf16 GEMM, C = A @ B^T, 64x64 wave tiles ----------------------
// NW = BM/32 waves (BM=128 -> 4 waves / 256 thr; BM=256 -> 8 waves / 512 thr).
// Wave tile 64x64: LDS reads/MFMA = 0.5 (vs 0.75 at 64x32) -> LDS pipe ~= MFMA pipe.
// 2-buf LDS, depth-1 prefetch with counted vmcnt; XOR swizzle both-sides (rule 21).
// EPI=0: Hout[t][col](ld 576) = bf16(relu(acc+bd[col]) * sg[t][col>>6])
// EPI=1: Cout[t][col](ld 1024) = acc   (bias folded into K via H2 tail)
template <int EPI, int NKT, int NBX, int BM>
__global__ __launch_bounds__(BM * 2, 2)
void gemm_bt(const ushort* __restrict__ A, const ushort* __restrict__ B,
             const float* __restrict__ sg, const float* __restrict__ bd,
             ushort* __restrict__ Hout, float* __restrict__ Cout, int nwg) {
  constexpr int K   = NKT * 64;
  constexpr int NW  = BM / 32;        // waves per block
  constexpr int AU  = BM / 8;         // 8-row staging units in A
  constexpr int TU  = AU + 16;        // + B units (128 rows)
  constexpr int UPW = TU / NW;        // staging units per wave (8 or 6)
  __shared__ __attribute__((aligned(16))) ushort sA[2][BM * 64];
  __shared__ __attribute__((aligned(16))) ushort sB[2][128 * 64];
  const int lane = threadIdx.x & 63;
  const int w    = threadIdx.x >> 6;
  const int lb = (blockIdx.x % 8) * (nwg / 8) + blockIdx.x / 8;  // XCD-chunked
  const int tile_m = (lb / NBX) * BM;
  const int tile_n = (lb % NBX) * 128;
  const int wm = (w >> 1) * 64;
  const int wn = (w & 1) * 64;
  const int sr = lane >> 3;
  const int sc = ((lane & 7) * 8) ^ (sr << 3);   // pre-swizzled source col
  const int lr = lane & 15;
  const int kg = lane >> 4;
  const int swz = (lr & 7) << 3;                 // read-side XOR (elems)
  f32x4 acc[4][4] = {};

#define STAGE(buf, kt) do {                                                         \
    const int k0_ = (kt) << 6;                                                      \
    _Pragma("unroll")                                                               \
    for (int c = 0; c < UPW; ++c) {                                                 \
      const int u = w * UPW + c;                                                    \
      if (u < AU) {                                                                 \
        const ushort* ga = A + (size_t)(tile_m + u * 8 + sr) * K + k0_ + sc;        \
        __builtin_amdgcn_global_load_lds((const __attribute__((address_space(1))) void*)ga, \
            (__attribute__((address_space(3))) void*)&sA[buf][u * 512], 16, 0, 0);  \
      } else {                                                                      \
        const ushort* gb = B + (size_t)(tile_n + (u - AU) * 8 + sr) * K + k0_ + sc; \
        __builtin_amdgcn_global_load_lds((const __attribute__((address_space(1))) void*)gb, \
            (__attribute__((address_space(3))) void*)&sB[buf][(u - AU) * 512], 16, 0, 0); \
      }                                                                             \
    } } while (0)

  STAGE(0, 0);
  for (int kt = 0; kt < NKT; ++kt) {
    const int cur = kt & 1;
    if (kt + 1 < NKT) {
      STAGE(cur ^ 1, kt + 1);
      if (UPW == 8) asm volatile("s_waitcnt vmcnt(8)" ::: "memory");
      else          asm volatile("s_waitcnt vmcnt(6)" ::: "memory");
    } else {
      asm volatile("s_waitcnt vmcnt(0)" ::: "memory");
    }
    __builtin_amdgcn_s_barrier();
    #pragma unroll
    for (int s = 0; s < 2; ++s) {
      bf16x8 af[4], bfr[4];
      #pragma unroll
      for (int i = 0; i < 4; ++i)
        af[i] = *(const bf16x8*)&sA[cur][(wm + i * 16 + lr) * 64 + ((s * 32 + kg * 8) ^ swz)];
      #pragma unroll
      for (int j = 0; j < 4; ++j)
        bfr[j] = *(const bf16x8*)&sB[cur][(wn + j * 16 + lr) * 64 + ((s * 32 + kg * 8) ^ swz)];
      __builtin_amdgcn_s_setprio(1);
      #pragma unroll
      for (int i = 0; i < 4; ++i)
        #pragma unroll
        for (int j = 0; j < 4; ++j)
          acc[i][j] = __builtin_amdgcn_mfma_f32_16x16x32_bf16(af[i], bfr[j], acc[i][j], 0, 0, 0);
      __builtin_amdgcn_s_setprio(0);
    }
    asm volatile("" ::: "memory");
    __builtin_amdgcn_s_barrier();
  }
#undef STAGE

  if (EPI == 0) {
    const int e = (tile_n + wn) >> 6;          // wave spans one expert column-block
    float bdv[4];
    #pragma unroll
    for (int j = 0; j < 4; ++j) bdv[j] = bd[tile_n + wn + j * 16 + lr];
    #pragma unroll
    for (int i = 0; i < 4; ++i) {
      #pragma unroll
      for (int r = 0; r < 4; ++r) {
        const int t = tile_m + wm + i * 16 + kg * 4 + r;
        const float sglv = sg[(size_t)t * NE + e];
        #pragma unroll
        for (int j = 0; j < 4; ++j) {
          float v = fmaxf(acc[i][j][r] + bdv[j], 0.f) * sglv;
          Hout[(size_t)t * HD2 + tile_n + wn + j * 16 + lr] = f2bf(v);
        }
      }
    }
  } else {
    #pragma unroll
    for (int i = 0; i < 4; ++i) {
      #pragma unroll
      for (int r = 0; r < 4; ++r) {
        const int t = tile_m + wm + i * 16 + kg * 4 + r;
        #pragma unroll
        for (int j = 0; j < 4; ++j)
          Cout[(size_t)t * DM + tile_n + wn + j * 16 + lr] = acc[i][j][r];
      }
    }
  }
}

extern "C" void kernel_launch(void* const* d_in, const int* in_sizes, int n_in,
                              void* d_out, int out_size, void* d_ws, size_t ws_size,
                              hipStream_t stream) {
  const float* x  = (const float*)d_in[0];
  const float* wg = (const float*)d_in[1];
  // d_in[2] = w_noise: unused (reference gates on clean logits)
  const float* Wd = (const float*)d_in[3];
  const float* bd = (const float*)d_in[4];
  const float* Wu = (const float*)d_in[5];
  const float* bu = (const float*)d_in[6];
  float* out = (float*)d_out;

  char* ws = (char*)d_ws;
  ushort* Xb   = (ushort*)(ws);                      // 16 MB
  ushort* H2   = (ushort*)(ws + 16777216);           // 9.44 MB
  ushort* WdT  = (ushort*)(ws + 26214400);           // 1 MB
  ushort* Wu2T = (ushort*)(ws + 27262976);           // 1.18 MB
  float*  sgw  = (float*) (ws + 28442624);           // 256 KB

  prep_cvt_kernel<<<dim3(NPREP + 272), dim3(256), 0, stream>>>(
      x, wg, Wd, Wu, bu, Xb, sgw, H2, WdT, Wu2T);

  // H2[:, :512] = sg .* relu(X @ WdT^T + bd):  M=8192 N=512 K=1024
  // 128x128 tiles, 4 waves: grid 64x4 = 256 blocks (2/CU)
  gemm_bt<0, 16, 4, 128><<<dim3(256), dim3(256), 0, stream>>>(
      Xb, WdT, sgw, bd, H2, nullptr, 256);
  // out = H2 @ Wu2T^T (bias folded):           M=8192 N=1024 K=576
  // 256x128 tiles, 8 waves: grid 32x8 = 256 blocks (1/CU)
  gemm_bt<1, 9, 8, 256><<<dim3(256), dim3(512), 0, stream>>>(
      H2, Wu2T, sgw, nullptr, nullptr, out, 256);
}

// Round 7
// 47.599 us; speedup vs baseline: 1.1121x; 1.1121x over previous
//
#include <hip/hip_runtime.h>
#include <stdint.h>

#define T_TOK 8192
#define DM    1024
#define NE    8
#define BOT   64
#define HD    512
#define HD2   576   // 512 expert cols + 8 sg cols + 56 zero pad (bias folded into K)
#define PW    8     // tokens per prep block
#define NPREP (T_TOK / PW)   // 1024 prep blocks

typedef __attribute__((ext_vector_type(8))) short bf16x8;
typedef __attribute__((ext_vector_type(4))) short bf16x4;
typedef __attribute__((ext_vector_type(4))) float f32x4;

__device__ __forceinline__ ushort f2bf(float f) {
  union { float f; uint32_t u; } v; v.f = f;
  uint32_t r = (v.u + 0x7fffu + ((v.u >> 16) & 1u)) >> 16;
  return (ushort)r;
}

// ---- merged prep (blocks 0..1023) + weight transposes (1024..1295) ---------
__global__ __launch_bounds__(256, 2)
void prep_cvt_kernel(const float* __restrict__ x, const float* __restrict__ wg,
                     const float* __restrict__ Wd, const float* __restrict__ Wu,
                     const float* __restrict__ bu,
                     ushort* __restrict__ Xb, float* __restrict__ sg,
                     ushort* __restrict__ H2, ushort* __restrict__ WdT,
                     ushort* __restrict__ Wu2T) {
  __shared__ float part[4][PW][NE];
  __shared__ float sgl[PW][NE];
  __shared__ ushort tl[64][72];
  if (blockIdx.x < NPREP) {
    const int lane = threadIdx.x & 63;
    const int w    = threadIdx.x >> 6;
    const int t0   = blockIdx.x * PW;
    const int dd   = w * 256 + lane * 4;
    float4 wgr[4][2];
    #pragma unroll
    for (int j = 0; j < 4; ++j) {
      wgr[j][0] = *(const float4*)(wg + (size_t)(dd + j) * NE);
      wgr[j][1] = *(const float4*)(wg + (size_t)(dd + j) * NE + 4);
    }
    const int ebit = ((lane & 1) << 2) | (lane & 2) | ((lane >> 2) & 1);
    const float* xp = x + (size_t)t0 * DM + dd;
    float4 xv = *(const float4*)xp;
    #pragma unroll
    for (int tk = 0; tk < PW; ++tk) {
      float4 nxt = {};
      if (tk + 1 < PW) nxt = *(const float4*)(xp + (size_t)(tk + 1) * DM);
      bf16x4 xb;
      xb[0] = (short)f2bf(xv.x); xb[1] = (short)f2bf(xv.y);
      xb[2] = (short)f2bf(xv.z); xb[3] = (short)f2bf(xv.w);
      *(bf16x4*)(Xb + (size_t)(t0 + tk) * DM + dd) = xb;
      float a[NE] = {};
      const float* xs = (const float*)&xv;
      #pragma unroll
      for (int j = 0; j < 4; ++j) {
        const float xj = xs[j];
        const float* wr = (const float*)&wgr[j][0];
        #pragma unroll
        for (int e = 0; e < NE; ++e) a[e] += xj * wr[e];
      }
      float t0v[4];
      #pragma unroll
      for (int j = 0; j < 4; ++j) {
        float send = (lane & 1) ? a[j] : a[j + 4];
        float keep = (lane & 1) ? a[j + 4] : a[j];
        t0v[j] = keep + __shfl_xor(send, 1);
      }
      float t1v[2];
      #pragma unroll
      for (int j = 0; j < 2; ++j) {
        float send = (lane & 2) ? t0v[j] : t0v[j + 2];
        float keep = (lane & 2) ? t0v[j + 2] : t0v[j];
        t1v[j] = keep + __shfl_xor(send, 2);
      }
      {
        float send = (lane & 4) ? t1v[0] : t1v[1];
        float keep = (lane & 4) ? t1v[1] : t1v[0];
        float t2 = keep + __shfl_xor(send, 4);
        t2 += __shfl_xor(t2, 8);
        t2 += __shfl_xor(t2, 16);
        t2 += __shfl_xor(t2, 32);
        if (lane < NE) part[w][tk][ebit] = t2;
      }
      xv = nxt;
    }
    __syncthreads();
    const int tid = threadIdx.x;
    if (tid < PW) {
      float lg[NE];
      #pragma unroll
      for (int e = 0; e < NE; ++e)
        lg[e] = part[0][tid][e] + part[1][tid][e] + part[2][tid][e] + part[3][tid][e];
      int e0 = 0; float l0 = lg[0];
      #pragma unroll
      for (int e = 1; e < NE; ++e) if (lg[e] > l0) { l0 = lg[e]; e0 = e; }
      int e1 = -1; float l1 = -3.4e38f;
      #pragma unroll
      for (int e = 0; e < NE; ++e) if (e != e0 && lg[e] > l1) { l1 = lg[e]; e1 = e; }
      const float p1  = __expf(l1 - l0);
      const float inv = 1.f / (1.f + p1);
      const float g0 = 0.5f * inv, g1 = 0.5f * p1 * inv;   // ADAPTER_SCALE folded
      float g[NE];
      #pragma unroll
      for (int e = 0; e < NE; ++e) g[e] = (e == e0) ? g0 : ((e == e1) ? g1 : 0.f);
      #pragma unroll
      for (int e = 0; e < NE; ++e) sgl[tid][e] = g[e];
      *(float4*)(sg + (size_t)(t0 + tid) * NE)     = *(float4*)&g[0];
      *(float4*)(sg + (size_t)(t0 + tid) * NE + 4) = *(float4*)&g[4];
    }
    __syncthreads();
    if (tid < PW * 8) {
      const int tk = tid >> 3, ch = tid & 7;
      bf16x8 v;
      #pragma unroll
      for (int k = 0; k < 8; ++k)
        v[k] = (ch == 0) ? (short)f2bf(sgl[tk][k]) : (short)0;
      *(bf16x8*)(H2 + (size_t)(t0 + tk) * HD2 + HD + ch * 8) = v;
    }
  } else {
    const int rr = threadIdx.x >> 2;
    const int cc = (threadIdx.x & 3) * 16;
    const int bx = blockIdx.x - NPREP;
    if (bx < 128) {
      const int e  = bx >> 4;
      const int d0 = (bx & 15) * 64;
      const float* src = Wd + ((size_t)e * DM + d0 + rr) * BOT + cc;
      #pragma unroll
      for (int i = 0; i < 4; ++i) {
        float4 v = *(const float4*)(src + i * 4);
        tl[rr][cc + i * 4 + 0] = f2bf(v.x);
        tl[rr][cc + i * 4 + 1] = f2bf(v.y);
        tl[rr][cc + i * 4 + 2] = f2bf(v.z);
        tl[rr][cc + i * 4 + 3] = f2bf(v.w);
      }
      __syncthreads();
      bf16x8 o0, o1;
      #pragma unroll
      for (int k = 0; k < 8; ++k) o0[k] = (short)tl[cc + k][rr];
      #pragma unroll
      for (int k = 0; k < 8; ++k) o1[k] = (short)tl[cc + 8 + k][rr];
      ushort* dst = WdT + ((size_t)e * BOT + rr) * DM + d0 + cc;
      *(bf16x8*)dst       = o0;
      *(bf16x8*)(dst + 8) = o1;
    } else {
      const int b2 = bx - 128;
      const int n0 = (b2 >> 4) * 64;
      const int d0 = (b2 & 15) * 64;
      const int n  = n0 + rr;
      #pragma unroll
      for (int i = 0; i < 4; ++i) {
        float4 v;
        if (n < HD)           v = *(const float4*)(Wu + (size_t)n * DM + d0 + cc + i * 4);
        else if (n < HD + NE) v = *(const float4*)(bu + (size_t)(n - HD) * DM + d0 + cc + i * 4);
        else { v.x = 0.f; v.y = 0.f; v.z = 0.f; v.w = 0.f; }
        tl[rr][cc + i * 4 + 0] = f2bf(v.x);
        tl[rr][cc + i * 4 + 1] = f2bf(v.y);
        tl[rr][cc + i * 4 + 2] = f2bf(v.z);
        tl[rr][cc + i * 4 + 3] = f2bf(v.w);
      }
      __syncthreads();
      bf16x8 o0, o1;
      #pragma unroll
      for (int k = 0; k < 8; ++k) o0[k] = (short)tl[cc + k][rr];
      #pragma unroll
      for (int k = 0; k < 8; ++k) o1[k] = (short)tl[cc + 8 + k][rr];
      ushort* dst = Wu2T + (size_t)(d0 + rr) * HD2 + n0 + cc;
      *(bf16x8*)dst       = o0;
      *(bf16x8*)(dst + 8) = o1;
    }
  }
}

// ---- 128(M)x64(N) bf16 GEMM, C = A @ B^T, 3-buf, ONE barrier per K-step -----
// Loop order: [vmcnt(6); barrier; compute(kt); STAGE(kt+2)].
//  - barrier after EVERY wave's vmcnt => buf[kt] fully staged & visible before
//    any wave computes kt (cross-wave safety, same guarantee as 2-barrier form).
//  - STAGE(kt+2) overwrites buf[(kt-1)%3]; all readers of it passed this
//    iteration's barrier => safe with a single barrier.
// LDS XOR-swizzled both-sides (rule 21); T5 setprio around MFMA clusters.
// EPI=0: Hout[t][col](ld 576) = bf16(relu(acc+bd[col]) * sg[t][col>>6])
// EPI=1: Cout[t][col](ld 1024) = acc   (bias folded into K via H2 tail)
template <int EPI, int NKT, int NBX>
__global__ __launch_bounds__(256)
void gemm_bt(const ushort* __restrict__ A, const ushort* __restrict__ B,
             const float* __restrict__ sg, const float* __restrict__ bd,
             ushort* __restrict__ Hout, float* __restrict__ Cout, int nwg) {
  constexpr int K = NKT * 64;
  __shared__ __attribute__((aligned(16))) ushort sA[3][128 * 64];
  __shared__ __attribute__((aligned(16))) ushort sB[3][64 * 64];
  const int lane = threadIdx.x & 63;
  const int w    = threadIdx.x >> 6;
  const int lb = (blockIdx.x % 8) * (nwg / 8) + blockIdx.x / 8;  // XCD-chunked
  const int tile_m = (lb / NBX) * 128;
  const int tile_n = (lb % NBX) * 64;
  const int wm = (w >> 1) * 64;
  const int wn = (w & 1) * 32;
  const int sr = lane >> 3;
  const int sc = ((lane & 7) * 8) ^ (sr << 3);   // pre-swizzled source col
  const int lr = lane & 15;
  const int kg = lane >> 4;
  const int swz = (lr & 7) << 3;                 // read-side XOR (elems)
  f32x4 acc[4][2] = {};

#define STAGE(buf, kt) do {                                                       \
    const int k0_ = (kt) << 6;                                                    \
    _Pragma("unroll")                                                             \
    for (int c = 0; c < 4; ++c) {                                                 \
      const ushort* ga = A + (size_t)(tile_m + w * 32 + c * 8 + sr) * K + k0_ + sc; \
      __builtin_amdgcn_global_load_lds((const __attribute__((address_space(1))) void*)ga, \
          (__attribute__((address_space(3))) void*)&sA[buf][(w * 32 + c * 8) * 64], 16, 0, 0); \
    }                                                                             \
    _Pragma("unroll")                                                             \
    for (int c = 0; c < 2; ++c) {                                                 \
      const ushort* gb = B + (size_t)(tile_n + w * 16 + c * 8 + sr) * K + k0_ + sc; \
      __builtin_amdgcn_global_load_lds((const __attribute__((address_space(1))) void*)gb, \
          (__attribute__((address_space(3))) void*)&sB[buf][(w * 16 + c * 8) * 64], 16, 0, 0); \
    } } while (0)

  STAGE(0, 0);
  STAGE(1, 1);
  for (int kt = 0; kt < NKT; ++kt) {
    const int cur = kt % 3;
    if (kt + 1 < NKT) asm volatile("s_waitcnt vmcnt(6)" ::: "memory");
    else              asm volatile("s_waitcnt vmcnt(0)" ::: "memory");
    __builtin_amdgcn_s_barrier();
    asm volatile("" ::: "memory");
    #pragma unroll
    for (int s = 0; s < 2; ++s) {
      bf16x8 af[4], bfr[2];
      #pragma unroll
      for (int i = 0; i < 4; ++i)
        af[i] = *(const bf16x8*)&sA[cur][(wm + i * 16 + lr) * 64 + ((s * 32 + kg * 8) ^ swz)];
      #pragma unroll
      for (int j = 0; j < 2; ++j)
        bfr[j] = *(const bf16x8*)&sB[cur][(wn + j * 16 + lr) * 64 + ((s * 32 + kg * 8) ^ swz)];
      __builtin_amdgcn_s_setprio(1);
      #pragma unroll
      for (int i = 0; i < 4; ++i)
        #pragma unroll
        for (int j = 0; j < 2; ++j)
          acc[i][j] = __builtin_amdgcn_mfma_f32_16x16x32_bf16(af[i], bfr[j], acc[i][j], 0, 0, 0);
      __builtin_amdgcn_s_setprio(0);
    }
    asm volatile("" ::: "memory");
    if (kt + 2 < NKT) STAGE((kt + 2) % 3, kt + 2);
  }
#undef STAGE

  if (EPI == 0) {
    const int e = tile_n >> 6;               // 64-col tile spans one expert
    float bdv[2];
    #pragma unroll
    for (int j = 0; j < 2; ++j) bdv[j] = bd[tile_n + wn + j * 16 + lr];
    #pragma unroll
    for (int i = 0; i < 4; ++i) {
      #pragma unroll
      for (int r = 0; r < 4; ++r) {
        const int t = tile_m + wm + i * 16 + kg * 4 + r;
        const float sglv = sg[(size_t)t * NE + e];
        #pragma unroll
        for (int j = 0; j < 2; ++j) {
          float v = fmaxf(acc[i][j][r] + bdv[j], 0.f) * sglv;
          Hout[(size_t)t * HD2 + tile_n + wn + j * 16 + lr] = f2bf(v);
        }
      }
    }
  } else {
    #pragma unroll
    for (int i = 0; i < 4; ++i) {
      #pragma unroll
      for (int r = 0; r < 4; ++r) {
        const int t = tile_m + wm + i * 16 + kg * 4 + r;
        #pragma unroll
        for (int j = 0; j < 2; ++j)
          Cout[(size_t)t * DM + tile_n + wn + j * 16 + lr] = acc[i][j][r];
      }
    }
  }
}

extern "C" void kernel_launch(void* const* d_in, const int* in_sizes, int n_in,
                              void* d_out, int out_size, void* d_ws, size_t ws_size,
                              hipStream_t stream) {
  const float* x  = (const float*)d_in[0];
  const float* wg = (const float*)d_in[1];
  // d_in[2] = w_noise: unused (reference gates on clean logits)
  const float* Wd = (const float*)d_in[3];
  const float* bd = (const float*)d_in[4];
  const float* Wu = (const float*)d_in[5];
  const float* bu = (const float*)d_in[6];
  float* out = (float*)d_out;

  char* ws = (char*)d_ws;
  ushort* Xb   = (ushort*)(ws);                      // 16 MB
  ushort* H2   = (ushort*)(ws + 16777216);           // 9.44 MB
  ushort* WdT  = (ushort*)(ws + 26214400);           // 1 MB
  ushort* Wu2T = (ushort*)(ws + 27262976);           // 1.18 MB
  float*  sgw  = (float*) (ws + 28442624);           // 256 KB

  prep_cvt_kernel<<<dim3(NPREP + 272), dim3(256), 0, stream>>>(
      x, wg, Wd, Wu, bu, Xb, sgw, H2, WdT, Wu2T);

  // H2[:, :512] = sg .* relu(X @ WdT^T + bd):  M=8192 N=512 K=1024
  // 128x64 tiles: grid 64x8 = 512 blocks (2/CU)
  gemm_bt<0, 16, 8><<<dim3(512), dim3(256), 0, stream>>>(
      Xb, WdT, sgw, bd, H2, nullptr, 512);
  // out = H2 @ Wu2T^T (bias folded):           M=8192 N=1024 K=576
  // 128x64 tiles: grid 64x16 = 1024 blocks
  gemm_bt<1, 9, 16><<<dim3(1024), dim3(256), 0, stream>>>(
      H2, Wu2T, sgw, nullptr, nullptr, out, 1024);
}